// Round 3
// baseline (363.291 us; speedup 1.0000x reference)
//
#include <hip/hip_runtime.h>
#include <hip/hip_bf16.h>

using bf16 = __hip_bfloat16;

#define BATCH 16
#define NNODE 2000
#define DIM   128
#define ODIM  64
#define NLAYER 3
#define BN    (BATCH*NNODE)   // 32000
#define NP1   (NNODE+1)       // 2001
#define CHK   125             // chunks per batch
#define CKS   16              // chunk size (125*16 = 2000)

// converted-input element offsets inside cvt buffer
#define OFF_COORDS 0
#define OFF_EW0    64000
#define OFF_EB0    64256
#define OFF_EW1    64384
#define OFF_EB1    80768
#define OFF_GW     80896
#define OFF_GA1    130048
#define OFF_GA2    130432
#define OFF_PW     130816
#define OFF_PB     139008
#define CVT_TOT    139072

// packed-weight offsets (ushort elements): [col][k] fragment order, hi plane then lo plane
#define PK_ENC     0                       // 2*16384
#define PK_GAT(l)  (32768 + (l)*32768)     // 2*16384 each
#define PK_PROJ    131072                  // 2*8192
#define PK_TOT     147456

typedef __attribute__((ext_vector_type(8))) short bf16x8;
typedef __attribute__((ext_vector_type(4))) float f32x4;

__device__ __forceinline__ unsigned short f2bf(float f){
    union { float f; unsigned u; } x; x.f = f;
    unsigned r = (x.u + 0x7FFFu + ((x.u >> 16) & 1u)) >> 16;
    return (unsigned short)r;
}
__device__ __forceinline__ float bf2f(unsigned short h){
    union { unsigned u; float f; } x; x.u = ((unsigned)h) << 16;
    return x.f;
}
// monotone float -> uint transform (total order, -inf..+inf ascending)
__device__ __forceinline__ unsigned ordu(float f){
    union { float f; unsigned u; } x; x.f = f;
    return (x.u & 0x80000000u) ? ~x.u : (x.u | 0x80000000u);
}

struct InPtrs { const void* p[10]; };

// ------------- convert ALL inputs to fp32 (sniff embedded per block) ---------------
__global__ void convert_all_k(InPtrs in, float* __restrict__ dst, float* __restrict__ flag)
{
    __shared__ int scnt[256];
    const unsigned short* raw = (const unsigned short*)in.p[0];
    int t = threadIdx.x, c = 0;
    for (int k = t; k < 2048; k += 256){
        unsigned short u = raw[2*k];                 // first 8 KB, safe either dtype
        int e = (u >> 7) & 0xFF;
        if (e >= 100 && e <= 140) ++c;
    }
    scnt[t] = c;
    __syncthreads();
    for (int s = 128; s; s >>= 1){ if (t < s) scnt[t] += scnt[t+s]; __syncthreads(); }
    const bool isbf16 = (scnt[0] >= 1800);
    if (blockIdx.x == 0 && t == 0) flag[0] = isbf16 ? 1.0f : 0.0f;

    const int off[11] = {OFF_COORDS,OFF_EW0,OFF_EB0,OFF_EW1,OFF_EB1,
                         OFF_GW,OFF_GA1,OFF_GA2,OFF_PW,OFF_PB,CVT_TOT};
    int i = blockIdx.x*256 + t;
    if (i >= CVT_TOT) return;
    int seg = 0;
    #pragma unroll
    for (int s = 1; s < 10; ++s) if (i >= off[s]) seg = s;
    int li = i - off[seg];
    if (isbf16) dst[i] = __bfloat162float(((const bf16*)in.p[seg])[li]);
    else        dst[i] = ((const float*)in.p[seg])[li];
}

// ------------- prep: pack weights to [col][k] bf16 hi/lo + wa = W@a vectors --------
__global__ __launch_bounds__(256) void prep_k(const float* __restrict__ cvt,
                                              unsigned short* __restrict__ pk,
                                              float* __restrict__ wa)
{
    const int mi = blockIdx.x, t = threadIdx.x;
    const float* W; unsigned short* dst; int N;
    if (mi == 0)      { W = cvt + OFF_EW1;                    dst = pk + PK_ENC;      N = 128; }
    else if (mi <= 3) { W = cvt + OFF_GW + (mi-1)*DIM*DIM;    dst = pk + PK_GAT(mi-1);N = 128; }
    else              { W = cvt + OFF_PW;                     dst = pk + PK_PROJ;     N = 64;  }
    const int tot = 128*N;
    unsigned short* dh = dst;
    unsigned short* dl = dst + tot;
    for (int e = t; e < tot; e += 256){
        int col = e >> 7, k = e & 127;            // dst layout [col][k], e == col*128+k
        float v = W[k*N + col];
        unsigned short hb = f2bf(v);
        unsigned short lb = f2bf(v - bf2f(hb));
        dh[e] = hb;
        dl[e] = lb;
    }
    if (mi >= 1 && mi <= 3){
        const int l = mi - 1;
        const float* av = cvt + ((t < 128) ? OFF_GA1 : OFF_GA2) + l*DIM;
        const int r = t & 127;
        float s = 0.f;
        for (int c2 = 0; c2 < 128; ++c2) s = fmaf(W[r*128 + c2], av[c2], s);
        wa[l*256 + (t >> 7)*128 + r] = s;
    }
}

// ---- shared MFMA helpers: A tile 64x128 staged as hi/lo bf16, XOR-swizzled --------
// LDS row stride 256 B; swizzle: byte_in_row ^= (row&7)<<4  (both write & read sides)

// ------------- fused encoder: h = relu(coords@w0+b0) @ w1 + b1  (split-bf16 MFMA) --
__global__ __launch_bounds__(256) void encmfma_k(const float* __restrict__ cvt,
    const unsigned short* __restrict__ pk, float* __restrict__ h)
{
    __shared__ unsigned short sAh[64*128], sAl[64*128];
    const int t = threadIdx.x, r0 = blockIdx.x*64;
    const int wv = t >> 6, l = t & 63, lc = l & 15, lk = l >> 4;
    const unsigned short* ph = pk;
    const unsigned short* pl = pk + 16384;
    bf16x8 bh[2][4], bl[2][4];
    #pragma unroll
    for (int cg = 0; cg < 2; ++cg){
        const int col = wv*32 + cg*16 + lc;
        #pragma unroll
        for (int kc = 0; kc < 4; ++kc){
            const int k0 = kc*32 + lk*8;
            bh[cg][kc] = *(const bf16x8*)&ph[col*128 + k0];
            bl[cg][kc] = *(const bf16x8*)&pl[col*128 + k0];
        }
    }
    const int row = t >> 2, g = t & 3;
    const float* coords = cvt + OFF_COORDS;
    const float* w0  = cvt + OFF_EW0;
    const float* b0v = cvt + OFF_EB0;
    const int node = r0 + row;
    const float c0 = coords[2*node], c1 = coords[2*node+1];
    char* shb = (char*)sAh; char* slb = (char*)sAl;
    const int swz = (row & 7) << 4;
    #pragma unroll
    for (int i = 0; i < 8; ++i){
        const int ch = g + i*4, k0 = ch*4;
        float4 wa0 = *(const float4*)&w0[k0];
        float4 wb0 = *(const float4*)&w0[DIM + k0];
        float4 bq  = *(const float4*)&b0v[k0];
        float4 v;
        v.x = fmaf(c0, wa0.x, fmaf(c1, wb0.x, bq.x)); v.x = v.x > 0.f ? v.x : 0.f;
        v.y = fmaf(c0, wa0.y, fmaf(c1, wb0.y, bq.y)); v.y = v.y > 0.f ? v.y : 0.f;
        v.z = fmaf(c0, wa0.z, fmaf(c1, wb0.z, bq.z)); v.z = v.z > 0.f ? v.z : 0.f;
        v.w = fmaf(c0, wa0.w, fmaf(c1, wb0.w, bq.w)); v.w = v.w > 0.f ? v.w : 0.f;
        ushort4 hq, lq;
        hq.x = f2bf(v.x); lq.x = f2bf(v.x - bf2f(hq.x));
        hq.y = f2bf(v.y); lq.y = f2bf(v.y - bf2f(hq.y));
        hq.z = f2bf(v.z); lq.z = f2bf(v.z - bf2f(hq.z));
        hq.w = f2bf(v.w); lq.w = f2bf(v.w - bf2f(hq.w));
        const int bo = (ch*8) ^ swz;
        *(ushort4*)(shb + row*256 + bo) = hq;
        *(ushort4*)(slb + row*256 + bo) = lq;
    }
    __syncthreads();
    f32x4 acc[4][2] = {};
    #pragma unroll
    for (int m = 0; m < 4; ++m){
        const int ar = m*16 + lc, asw = (ar & 7) << 4;
        #pragma unroll
        for (int kc = 0; kc < 4; ++kc){
            const int bo = (kc*64 + lk*16) ^ asw;
            bf16x8 ah = *(bf16x8*)(shb + ar*256 + bo);
            bf16x8 al = *(bf16x8*)(slb + ar*256 + bo);
            #pragma unroll
            for (int cg = 0; cg < 2; ++cg){
                acc[m][cg] = __builtin_amdgcn_mfma_f32_16x16x32_bf16(ah, bh[cg][kc], acc[m][cg], 0, 0, 0);
                acc[m][cg] = __builtin_amdgcn_mfma_f32_16x16x32_bf16(ah, bl[cg][kc], acc[m][cg], 0, 0, 0);
                acc[m][cg] = __builtin_amdgcn_mfma_f32_16x16x32_bf16(al, bh[cg][kc], acc[m][cg], 0, 0, 0);
            }
        }
    }
    const float* eb1 = cvt + OFF_EB1;
    #pragma unroll
    for (int m = 0; m < 4; ++m){
        const int rg = r0 + m*16 + lk*4;
        #pragma unroll
        for (int cg = 0; cg < 2; ++cg){
            const int col = wv*32 + cg*16 + lc;
            const float bb = eb1[col];
            #pragma unroll
            for (int j = 0; j < 4; ++j) h[(size_t)(rg+j)*DIM + col] = acc[m][cg][j] + bb;
        }
    }
}

// ------------- GAT GEMM: Wh = h @ W (split-bf16 MFMA) + full e1/e2 via h@(W@a) -----
__global__ __launch_bounds__(256) void gatmfma_k(const float* __restrict__ A,
    const unsigned short* __restrict__ pk, const float* __restrict__ wa,
    float* __restrict__ Wh, float* __restrict__ e1p, float* __restrict__ e2p)
{
    __shared__ unsigned short sAh[64*128], sAl[64*128];
    const int t = threadIdx.x, r0 = blockIdx.x*64;
    const int wv = t >> 6, l = t & 63, lc = l & 15, lk = l >> 4;
    const unsigned short* ph = pk;
    const unsigned short* pl = pk + 16384;
    bf16x8 bh[2][4], bl[2][4];
    #pragma unroll
    for (int cg = 0; cg < 2; ++cg){
        const int col = wv*32 + cg*16 + lc;
        #pragma unroll
        for (int kc = 0; kc < 4; ++kc){
            const int k0 = kc*32 + lk*8;
            bh[cg][kc] = *(const bf16x8*)&ph[col*128 + k0];
            bl[cg][kc] = *(const bf16x8*)&pl[col*128 + k0];
        }
    }
    const int row = t >> 2, g = t & 3;
    const float* Ar = A + (size_t)(r0 + row)*DIM;
    char* shb = (char*)sAh; char* slb = (char*)sAl;
    const int swz = (row & 7) << 4;
    float e1 = 0.f, e2 = 0.f;
    #pragma unroll
    for (int i = 0; i < 8; ++i){
        const int ch = g + i*4;
        float4 a  = *(const float4*)&Ar[ch*4];
        float4 u1 = *(const float4*)&wa[ch*4];
        float4 u2 = *(const float4*)&wa[128 + ch*4];
        e1 = fmaf(a.x,u1.x, fmaf(a.y,u1.y, fmaf(a.z,u1.z, fmaf(a.w,u1.w, e1))));
        e2 = fmaf(a.x,u2.x, fmaf(a.y,u2.y, fmaf(a.z,u2.z, fmaf(a.w,u2.w, e2))));
        ushort4 hq, lq;
        hq.x = f2bf(a.x); lq.x = f2bf(a.x - bf2f(hq.x));
        hq.y = f2bf(a.y); lq.y = f2bf(a.y - bf2f(hq.y));
        hq.z = f2bf(a.z); lq.z = f2bf(a.z - bf2f(hq.z));
        hq.w = f2bf(a.w); lq.w = f2bf(a.w - bf2f(hq.w));
        const int bo = (ch*8) ^ swz;
        *(ushort4*)(shb + row*256 + bo) = hq;
        *(ushort4*)(slb + row*256 + bo) = lq;
    }
    e1 += __shfl_xor(e1, 1); e1 += __shfl_xor(e1, 2);
    e2 += __shfl_xor(e2, 1); e2 += __shfl_xor(e2, 2);
    if (g == 0){ e1p[r0 + row] = e1; e2p[r0 + row] = e2; }
    __syncthreads();
    f32x4 acc[4][2] = {};
    #pragma unroll
    for (int m = 0; m < 4; ++m){
        const int ar = m*16 + lc, asw = (ar & 7) << 4;
        #pragma unroll
        for (int kc = 0; kc < 4; ++kc){
            const int bo = (kc*64 + lk*16) ^ asw;
            bf16x8 ah = *(bf16x8*)(shb + ar*256 + bo);
            bf16x8 al = *(bf16x8*)(slb + ar*256 + bo);
            #pragma unroll
            for (int cg = 0; cg < 2; ++cg){
                acc[m][cg] = __builtin_amdgcn_mfma_f32_16x16x32_bf16(ah, bh[cg][kc], acc[m][cg], 0, 0, 0);
                acc[m][cg] = __builtin_amdgcn_mfma_f32_16x16x32_bf16(ah, bl[cg][kc], acc[m][cg], 0, 0, 0);
                acc[m][cg] = __builtin_amdgcn_mfma_f32_16x16x32_bf16(al, bh[cg][kc], acc[m][cg], 0, 0, 0);
            }
        }
    }
    #pragma unroll
    for (int m = 0; m < 4; ++m){
        const int rg = r0 + m*16 + lk*4;
        #pragma unroll
        for (int cg = 0; cg < 2; ++cg){
            const int col = wv*32 + cg*16 + lc;
            #pragma unroll
            for (int j = 0; j < 4; ++j) Wh[(size_t)(rg+j)*DIM + col] = acc[m][cg][j];
        }
    }
}

// ------------- final projection GEMM (split-bf16 MFMA), output dtype per flag ------
__global__ __launch_bounds__(256) void projmfma_k(const float* __restrict__ A,
    const unsigned short* __restrict__ pk, const float* __restrict__ bias,
    void* __restrict__ outp, const float* __restrict__ flag)
{
    __shared__ unsigned short sAh[64*128], sAl[64*128];
    const int t = threadIdx.x, r0 = blockIdx.x*64;
    const int wv = t >> 6, l = t & 63, lc = l & 15, lk = l >> 4;
    const unsigned short* ph = pk;
    const unsigned short* pl = pk + 8192;
    bf16x8 bh[4], bl[4];
    const int col = wv*16 + lc;
    #pragma unroll
    for (int kc = 0; kc < 4; ++kc){
        const int k0 = kc*32 + lk*8;
        bh[kc] = *(const bf16x8*)&ph[col*128 + k0];
        bl[kc] = *(const bf16x8*)&pl[col*128 + k0];
    }
    const int row = t >> 2, g = t & 3;
    const float* Ar = A + (size_t)(r0 + row)*DIM;
    char* shb = (char*)sAh; char* slb = (char*)sAl;
    const int swz = (row & 7) << 4;
    #pragma unroll
    for (int i = 0; i < 8; ++i){
        const int ch = g + i*4;
        float4 a = *(const float4*)&Ar[ch*4];
        ushort4 hq, lq;
        hq.x = f2bf(a.x); lq.x = f2bf(a.x - bf2f(hq.x));
        hq.y = f2bf(a.y); lq.y = f2bf(a.y - bf2f(hq.y));
        hq.z = f2bf(a.z); lq.z = f2bf(a.z - bf2f(hq.z));
        hq.w = f2bf(a.w); lq.w = f2bf(a.w - bf2f(hq.w));
        const int bo = (ch*8) ^ swz;
        *(ushort4*)(shb + row*256 + bo) = hq;
        *(ushort4*)(slb + row*256 + bo) = lq;
    }
    __syncthreads();
    f32x4 acc[4] = {};
    #pragma unroll
    for (int m = 0; m < 4; ++m){
        const int ar = m*16 + lc, asw = (ar & 7) << 4;
        #pragma unroll
        for (int kc = 0; kc < 4; ++kc){
            const int bo = (kc*64 + lk*16) ^ asw;
            bf16x8 ah = *(bf16x8*)(shb + ar*256 + bo);
            bf16x8 al = *(bf16x8*)(slb + ar*256 + bo);
            acc[m] = __builtin_amdgcn_mfma_f32_16x16x32_bf16(ah, bh[kc], acc[m], 0, 0, 0);
            acc[m] = __builtin_amdgcn_mfma_f32_16x16x32_bf16(ah, bl[kc], acc[m], 0, 0, 0);
            acc[m] = __builtin_amdgcn_mfma_f32_16x16x32_bf16(al, bh[kc], acc[m], 0, 0, 0);
        }
    }
    const float bb = bias[col];
    const bool isbf = (flag[0] != 0.0f);
    #pragma unroll
    for (int m = 0; m < 4; ++m){
        const int rg = r0 + m*16 + lk*4;
        #pragma unroll
        for (int j = 0; j < 4; ++j){
            float v = acc[m][j] + bb;
            size_t p = (size_t)(rg+j)*ODIM + col;
            if (isbf) ((bf16*)outp)[p] = __float2bfloat16(v);
            else      ((float*)outp)[p] = v;
        }
    }
}

// ------------- per-batch rank (replaces bitonic sort): brute-force u64-key ranking --
// key = (ordered_uint(e2) << 32) | idx  -> unique keys, rank = #{smaller} is a
// permutation. 8 blocks/batch x 256 thr; each thread ranks one element by scanning
// all 2000 keys staged in LDS (broadcast ds_read_b128, conflict-free).
__global__ __launch_bounds__(256) void rank_k(const float* __restrict__ e2p,
    float* __restrict__ e2s, int* __restrict__ sidx,
    float* __restrict__ wp, float* __restrict__ wn, float* __restrict__ e2m)
{
    __shared__ __align__(16) unsigned long long skey[2000];
    __shared__ float smax[4];
    const int b = blockIdx.x >> 3, blk = blockIdx.x & 7, t = threadIdx.x;
    const int base = b*NNODE;
    float pm = -3.0e38f;
    for (int k = t; k < NNODE; k += 256){
        float v = e2p[base + k];
        pm = fmaxf(pm, v);
        skey[k] = ((unsigned long long)ordu(v) << 32) | (unsigned)k;
    }
    #pragma unroll
    for (int m = 32; m; m >>= 1) pm = fmaxf(pm, __shfl_xor(pm, m));
    if ((t & 63) == 0) smax[t >> 6] = pm;
    __syncthreads();
    const float mx = fmaxf(fmaxf(smax[0], smax[1]), fmaxf(smax[2], smax[3]));
    if (blk == 0 && t == 0) e2m[b] = mx;

    const int i = blk*256 + t;
    if (i >= NNODE) return;
    const float vi = e2p[base + i];
    const unsigned long long ki = ((unsigned long long)ordu(vi) << 32) | (unsigned)i;
    unsigned r = 0;
    const ulonglong2* sk2 = (const ulonglong2*)skey;
    #pragma unroll 4
    for (int j2 = 0; j2 < NNODE/2; ++j2){
        ulonglong2 w = sk2[j2];
        r += (w.x < ki);
        r += (w.y < ki);
    }
    e2s [base + r] = vi;
    sidx[base + r] = i;
    wp  [base + r] = __expf(vi - mx);
    wn  [base + r] = __expf(0.2f*(vi - mx));
}

// ------------- pass A: per-chunk partial sums (vector[D] + scalar) ----------------
__global__ void passA_k(const float* __restrict__ Wh, const int* __restrict__ sidx,
    const float* __restrict__ wp, const float* __restrict__ wn,
    float* __restrict__ chunkP, float* __restrict__ chunkN,
    float* __restrict__ schunkP, float* __restrict__ schunkN)
{
    const int b = blockIdx.x / CHK, c = blockIdx.x % CHK, d = threadIdx.x;
    const int base = b*NNODE;
    float sp=0.f, sn=0.f, ssp=0.f, ssn=0.f;
    #pragma unroll 4
    for (int r = c*CKS; r < c*CKS + CKS; ++r){
        int j = sidx[base + r];
        float whv = Wh[((size_t)base + j)*DIM + d];
        float wpv = wp[base + r], wnv = wn[base + r];
        sp = fmaf(wpv, whv, sp);  sn = fmaf(wnv, whv, sn);
        ssp += wpv;  ssn += wnv;
    }
    const int idx = b*CHK + c;
    chunkP[idx*DIM + d] = sp;
    chunkN[idx*DIM + d] = sn;
    if (d == 0){ schunkP[idx] = ssp; schunkN[idx] = ssn; }
}

// ------------- pass B: cross-chunk suffix (P) / prefix (N) offsets (exclusive) -----
__global__ __launch_bounds__(256) void passB_k(
    const float* __restrict__ chunkP, const float* __restrict__ chunkN,
    const float* __restrict__ schunkP, const float* __restrict__ schunkN,
    float* __restrict__ offP, float* __restrict__ offN,
    float* __restrict__ soffP, float* __restrict__ soffN)
{
    const int b = blockIdx.x, tid = threadIdx.x;
    const bool doP = (blockIdx.y == 0);
    const float* chunk  = doP ? chunkP  : chunkN;
    const float* schunk = doP ? schunkP : schunkN;
    float* off  = doP ? offP  : offN;
    float* soff = doP ? soffP : soffN;

    if (tid < 128){
        const int d = tid;
        float acc = 0.f, v[25];
        #pragma unroll
        for (int t = 0; t < 5; ++t){
            const int c0 = doP ? (4-t)*25 : t*25;
            #pragma unroll
            for (int k = 0; k < 25; ++k) v[k] = chunk[(b*CHK + c0 + k)*DIM + d];
            if (doP){
                #pragma unroll
                for (int k = 24; k >= 0; --k){ off[(b*CHK + c0 + k)*DIM + d] = acc; acc += v[k]; }
            } else {
                #pragma unroll
                for (int k = 0; k < 25; ++k){ off[(b*CHK + c0 + k)*DIM + d] = acc; acc += v[k]; }
            }
        }
    } else if (tid == 128){
        float sacc = 0.f, sv[25];
        #pragma unroll
        for (int t = 0; t < 5; ++t){
            const int c0 = doP ? (4-t)*25 : t*25;
            #pragma unroll
            for (int k = 0; k < 25; ++k) sv[k] = schunk[b*CHK + c0 + k];
            if (doP){
                #pragma unroll
                for (int k = 24; k >= 0; --k){ soff[b*CHK + c0 + k] = sacc; sacc += sv[k]; }
            } else {
                #pragma unroll
                for (int k = 0; k < 25; ++k){ soff[b*CHK + c0 + k] = sacc; sacc += sv[k]; }
            }
        }
    }
}

// ------------- pass C: full suffix (pos) / prefix (neg) arrays over sorted order ---
__global__ void passC_k(const float* __restrict__ Wh, const int* __restrict__ sidx,
    const float* __restrict__ wp, const float* __restrict__ wn,
    const float* __restrict__ offP, const float* __restrict__ offN,
    const float* __restrict__ soffP, const float* __restrict__ soffN,
    float* __restrict__ Ppos, float* __restrict__ Pneg,
    float* __restrict__ pposs, float* __restrict__ pnegs)
{
    const int b = blockIdx.x / CHK, c = blockIdx.x % CHK, d = threadIdx.x;
    const int base = b*NNODE;
    const size_t pb = (size_t)b*NP1;
    const int idx = b*CHK + c;
    const int r0 = c*CKS, r1 = r0 + CKS;

    if (c == CHK-1){
        Ppos[(pb + NNODE)*DIM + d] = 0.f;
        if (d == 0) pposs[pb + NNODE] = 0.f;
    }
    float pr = offP[idx*DIM + d], spr = soffP[idx];
    for (int r = r1-1; r >= r0; --r){
        int j = sidx[base + r];
        float whv = Wh[((size_t)base + j)*DIM + d];
        float wpv = wp[base + r];
        pr  = fmaf(wpv, whv, pr);
        spr += wpv;
        Ppos[(pb + r)*DIM + d] = pr;
        if (d == 0) pposs[pb + r] = spr;
    }
    float nr = offN[idx*DIM + d], snr = soffN[idx];
    for (int r = r0; r < r1; ++r){
        int j = sidx[base + r];
        float whv = Wh[((size_t)base + j)*DIM + d];
        float wnv = wn[base + r];
        Pneg[(pb + r)*DIM + d] = nr;
        if (d == 0) pnegs[pb + r] = snr;
        nr  = fmaf(wnv, whv, nr);
        snr += wnv;
    }
    if (c == CHK-1){
        Pneg[(pb + NNODE)*DIM + d] = nr;
        if (d == 0) pnegs[pb + NNODE] = snr;
    }
}

// ------------- output, 16 rows per block: parallel binsearch then stream -----------
__global__ __launch_bounds__(128) void out16_k(const float* __restrict__ e1p,
    const float* __restrict__ e2s, const float* __restrict__ e2m,
    const float* __restrict__ Ppos, const float* __restrict__ Pneg,
    const float* __restrict__ pposs, const float* __restrict__ pnegs, float* __restrict__ h)
{
    __shared__ int   slo[CKS];
    __shared__ float sps[CKS], sns[CKS];
    const int b = blockIdx.x / CHK, c = blockIdx.x % CHK, d = threadIdx.x;
    const int base = b*NNODE, r0 = c*CKS;
    const size_t pb = (size_t)b*NP1;

    if (d < CKS){
        int row = base + r0 + d;
        float e1v = e1p[row];
        float s = e1v + e2m[b];
        float m = (s >= 0.f) ? s : 0.2f*s;
        sps[d] = __expf(s - m);
        sns[d] = __expf(0.2f*s - m);
        const float* es = e2s + base;
        float tt = -e1v;
        int lo = 0, hi = NNODE;
        while (lo < hi){ int mid = (lo+hi) >> 1; if (es[mid] < tt) lo = mid+1; else hi = mid; }
        slo[d] = lo;
    }
    __syncthreads();
    #pragma unroll 4
    for (int k = 0; k < CKS; ++k){
        int row = base + r0 + k;
        size_t kb = pb + slo[k];
        float numer = sps[k]*Ppos[kb*DIM + d] + sns[k]*Pneg[kb*DIM + d];
        float Z     = sps[k]*pposs[kb]        + sns[k]*pnegs[kb];
        float q = numer / Z;
        h[(size_t)row*DIM + d] = (q > 0.f) ? q : ((q == q) ? 0.f : q);
    }
}

extern "C" void kernel_launch(void* const* d_in, const int* in_sizes, int n_in,
                              void* d_out, int out_size, void* d_ws, size_t ws_size,
                              hipStream_t stream)
{
    (void)in_sizes; (void)n_in; (void)out_size; (void)ws_size;

    float* f = (float*)d_ws;
    float* flag    = f;  f += 4;
    float* cvt     = f;  f += CVT_TOT;                 // 0.56 MB
    float* h       = f;  f += (size_t)BN*DIM;          // 16.4 MB
    float* Wh      = f;  f += (size_t)BN*DIM;          // 16.4 MB
    float* Ppos    = f;  f += (size_t)BATCH*NP1*DIM;   // 16.4 MB
    float* Pneg    = f;  f += (size_t)BATCH*NP1*DIM;   // 16.4 MB
    float* chunkP  = f;  f += BATCH*CHK*DIM;           // 1 MB
    float* chunkN  = f;  f += BATCH*CHK*DIM;           // 1 MB
    float* offP    = f;  f += BATCH*CHK*DIM;           // 1 MB
    float* offN    = f;  f += BATCH*CHK*DIM;           // 1 MB
    float* schunkP = f;  f += BATCH*CHK;
    float* schunkN = f;  f += BATCH*CHK;
    float* soffP   = f;  f += BATCH*CHK;
    float* soffN   = f;  f += BATCH*CHK;
    float* e1p     = f;  f += BN;                      // full e1 (no partials)
    float* e2p     = f;  f += BN;                      // full e2
    float* e2s     = f;  f += BN;
    float* wp      = f;  f += BN;
    float* wn      = f;  f += BN;
    float* pposs   = f;  f += BATCH*NP1;
    float* pnegs   = f;  f += BATCH*NP1;
    float* e2m     = f;  f += 16;
    int*   sidx    = (int*)f;
    unsigned short* pk = (unsigned short*)(sidx + BN);   // 16B-aligned (all counts %4==0)
    float* wa      = (float*)(pk + PK_TOT);              // 3 layers x {wa1,wa2}[128]

    // 1. convert all inputs to fp32 (sniff embedded)
    InPtrs ip;
    for (int i = 0; i < 10; ++i) ip.p[i] = d_in[i];
    convert_all_k<<<(CVT_TOT+255)/256, 256, 0, stream>>>(ip, cvt, flag);

    // 2. pack weights to bf16 hi/lo fragment order + wa = W@a vectors
    prep_k<<<5, 256, 0, stream>>>(cvt, pk, wa);

    // 3. fused encoder (enc0 + split-bf16 MFMA gemm)
    encmfma_k<<<BN/64, 256, 0, stream>>>(cvt, pk + PK_ENC, h);

    // 4. GAT layers (exact separable-softmax factorization)
    for (int l = 0; l < NLAYER; ++l){
        gatmfma_k<<<BN/64, 256, 0, stream>>>(h, pk + PK_GAT(l), wa + l*256, Wh, e1p, e2p);
        rank_k<<<BATCH*8, 256, 0, stream>>>(e2p, e2s, sidx, wp, wn, e2m);
        passA_k<<<BATCH*CHK, DIM, 0, stream>>>(Wh, sidx, wp, wn, chunkP, chunkN, schunkP, schunkN);
        passB_k<<<dim3(BATCH, 2), 256, 0, stream>>>(chunkP, chunkN, schunkP, schunkN,
                                                    offP, offN, soffP, soffN);
        passC_k<<<BATCH*CHK, DIM, 0, stream>>>(Wh, sidx, wp, wn, offP, offN, soffP, soffN,
                                               Ppos, Pneg, pposs, pnegs);
        out16_k<<<BATCH*CHK, DIM, 0, stream>>>(e1p, e2s, e2m, Ppos, Pneg, pposs, pnegs, h);
    }

    // 5. projection (split-bf16 MFMA), output dtype per flag
    projmfma_k<<<BN/64, 256, 0, stream>>>(h, pk + PK_PROJ, cvt + OFF_PB, d_out, flag);
}

// Round 4
// 301.880 us; speedup vs baseline: 1.2034x; 1.2034x over previous
//
#include <hip/hip_runtime.h>
#include <hip/hip_bf16.h>

using bf16 = __hip_bfloat16;

#define BATCH 16
#define NNODE 2000
#define DIM   128
#define ODIM  64
#define NLAYER 3
#define BN    (BATCH*NNODE)   // 32000
#define NP1   (NNODE+1)       // 2001
#define CHK   125             // chunks per batch
#define CKS   16              // chunk size (125*16 = 2000)

// converted-input element offsets inside cvt buffer
#define OFF_COORDS 0
#define OFF_EW0    64000
#define OFF_EB0    64256
#define OFF_EW1    64384
#define OFF_EB1    80768
#define OFF_GW     80896
#define OFF_GA1    130048
#define OFF_GA2    130432
#define OFF_PW     130816
#define OFF_PB     139008
#define CVT_TOT    139072

// packed-weight offsets (ushort elements): [col][k] fragment order, hi plane then lo plane
// layer-0 slot holds Wfuse = enc_w1 @ gat_W[0] (encoder folded in)
#define PK_GAT(l)  (32768 + (l)*32768)     // 2*16384 each
#define PK_PROJ    131072                  // 2*8192
#define PK_TOT     147456

typedef __attribute__((ext_vector_type(8))) short bf16x8;
typedef __attribute__((ext_vector_type(4))) float f32x4;

__device__ __forceinline__ unsigned short f2bf(float f){
    union { float f; unsigned u; } x; x.f = f;
    unsigned r = (x.u + 0x7FFFu + ((x.u >> 16) & 1u)) >> 16;
    return (unsigned short)r;
}
__device__ __forceinline__ float bf2f(unsigned short h){
    union { unsigned u; float f; } x; x.u = ((unsigned)h) << 16;
    return x.f;
}
// monotone float -> uint transform (total order) and inverse
__device__ __forceinline__ unsigned ordu(float f){
    union { float f; unsigned u; } x; x.f = f;
    return (x.u & 0x80000000u) ? ~x.u : (x.u | 0x80000000u);
}
__device__ __forceinline__ float iordu(unsigned u){
    union { unsigned u; float f; } x;
    x.u = (u & 0x80000000u) ? (u ^ 0x80000000u) : ~u;
    return x.f;
}

struct InPtrs { const void* p[10]; };

// ------------- convert ALL inputs to fp32 (sniff embedded per block) ---------------
__global__ void convert_all_k(InPtrs in, float* __restrict__ dst, float* __restrict__ flag)
{
    __shared__ int scnt[256];
    const unsigned short* raw = (const unsigned short*)in.p[0];
    int t = threadIdx.x, c = 0;
    for (int k = t; k < 2048; k += 256){
        unsigned short u = raw[2*k];                 // first 8 KB, safe either dtype
        int e = (u >> 7) & 0xFF;
        if (e >= 100 && e <= 140) ++c;
    }
    scnt[t] = c;
    __syncthreads();
    for (int s = 128; s; s >>= 1){ if (t < s) scnt[t] += scnt[t+s]; __syncthreads(); }
    const bool isbf16 = (scnt[0] >= 1800);
    if (blockIdx.x == 0 && t == 0) flag[0] = isbf16 ? 1.0f : 0.0f;

    const int off[11] = {OFF_COORDS,OFF_EW0,OFF_EB0,OFF_EW1,OFF_EB1,
                         OFF_GW,OFF_GA1,OFF_GA2,OFF_PW,OFF_PB,CVT_TOT};
    int i = blockIdx.x*256 + t;
    if (i >= CVT_TOT) return;
    int seg = 0;
    #pragma unroll
    for (int s = 1; s < 10; ++s) if (i >= off[s]) seg = s;
    int li = i - off[seg];
    if (isbf16) dst[i] = __bfloat162float(((const bf16*)in.p[seg])[li]);
    else        dst[i] = ((const float*)in.p[seg])[li];
}

// ------------- prep: pack W layers 1,2 + proj to bf16 hi/lo; wa = W@a vectors ------
__global__ __launch_bounds__(256) void prep_k(const float* __restrict__ cvt,
                                              unsigned short* __restrict__ pk,
                                              float* __restrict__ wa)
{
    const int mi = blockIdx.x, t = threadIdx.x;
    if (mi < 3){
        const float* W; unsigned short* dst; int N;
        if (mi == 0)      { W = cvt + OFF_GW + 1*DIM*DIM;  dst = pk + PK_GAT(1); N = 128; }
        else if (mi == 1) { W = cvt + OFF_GW + 2*DIM*DIM;  dst = pk + PK_GAT(2); N = 128; }
        else              { W = cvt + OFF_PW;              dst = pk + PK_PROJ;   N = 64;  }
        const int tot = 128*N;
        unsigned short* dh = dst;
        unsigned short* dl = dst + tot;
        for (int e = t; e < tot; e += 256){
            int col = e >> 7, k = e & 127;            // dst layout [col][k]
            float v = W[k*N + col];
            unsigned short hb = f2bf(v);
            unsigned short lb = f2bf(v - bf2f(hb));
            dh[e] = hb;
            dl[e] = lb;
        }
    } else {
        // wa[l*256 + half*128 + r] = (gat_W[l] @ a_half[l])[r]
        for (int idx = t; idx < 3*256; idx += 256){
            const int l = idx >> 8, rem = idx & 255, half = rem >> 7, r = rem & 127;
            const float* W  = cvt + OFF_GW + l*DIM*DIM;
            const float* av = cvt + (half ? OFF_GA2 : OFF_GA1) + l*DIM;
            float s = 0.f;
            for (int c2 = 0; c2 < 128; ++c2) s = fmaf(W[r*128 + c2], av[c2], s);
            wa[l*256 + half*128 + r] = s;
        }
    }
}

// ------------- prep2: Wfuse = w1@W0 (packed), bfuse = b1@W0, u1/u2, s1/s2 ----------
__global__ __launch_bounds__(128) void prep2_k(const float* __restrict__ cvt,
    unsigned short* __restrict__ pk, const float* __restrict__ wa,
    float* __restrict__ u12, float* __restrict__ bfuse, float* __restrict__ su)
{
    const int b = blockIdx.x, t = threadIdx.x;
    const float* w1 = cvt + OFF_EW1;
    const float* W0 = cvt + OFF_GW;
    if (b < 128){
        float acc = 0.f;
        for (int d = 0; d < 128; ++d) acc = fmaf(w1[b*DIM + d], W0[d*DIM + t], acc);
        unsigned short hb = f2bf(acc), lb = f2bf(acc - bf2f(hb));
        unsigned short* dst = pk + PK_GAT(0);
        dst[t*128 + b]         = hb;      // [col=t][k=b] hi plane
        dst[16384 + t*128 + b] = lb;      // lo plane
    } else if (b == 128){
        const float* b1 = cvt + OFF_EB1;
        float acc = 0.f;
        for (int d = 0; d < 128; ++d) acc = fmaf(b1[d], W0[d*DIM + t], acc);
        bfuse[t] = acc;
        if (t < 2){
            float s = 0.f;
            for (int d = 0; d < 128; ++d) s = fmaf(b1[d], wa[t*128 + d], s);
            su[t] = s;
        }
    } else {
        float a1 = 0.f, a2 = 0.f;
        for (int d = 0; d < 128; ++d){
            float w = w1[t*DIM + d];
            a1 = fmaf(w, wa[d],       a1);
            a2 = fmaf(w, wa[128 + d], a2);
        }
        u12[t]       = a1;
        u12[128 + t] = a2;
    }
}

// ---- shared MFMA convention: A tile 64x128 staged as hi/lo bf16, XOR-swizzled -----
// LDS row stride 256 B; swizzle: byte_in_row ^= (row&7)<<4  (both write & read sides)

// ------------- layer-0 GAT: encoder folded in. A1 = relu(coords@w0+b0) inline ------
__global__ __launch_bounds__(256) void gat0mfma_k(const float* __restrict__ cvt,
    const unsigned short* __restrict__ pk, const float* __restrict__ u12,
    const float* __restrict__ su, const float* __restrict__ bfuse,
    float* __restrict__ Wh, float* __restrict__ e1p, float* __restrict__ e2p)
{
    __shared__ unsigned short sAh[64*128], sAl[64*128];
    const int t = threadIdx.x, r0 = blockIdx.x*64;
    const int wv = t >> 6, l = t & 63, lc = l & 15, lk = l >> 4;
    const unsigned short* ph = pk;
    const unsigned short* pl = pk + 16384;
    bf16x8 bh[2][4], bl[2][4];
    #pragma unroll
    for (int cg = 0; cg < 2; ++cg){
        const int col = wv*32 + cg*16 + lc;
        #pragma unroll
        for (int kc = 0; kc < 4; ++kc){
            const int k0 = kc*32 + lk*8;
            bh[cg][kc] = *(const bf16x8*)&ph[col*128 + k0];
            bl[cg][kc] = *(const bf16x8*)&pl[col*128 + k0];
        }
    }
    const int row = t >> 2, g = t & 3;
    const float* coords = cvt + OFF_COORDS;
    const float* w0  = cvt + OFF_EW0;
    const float* b0v = cvt + OFF_EB0;
    const int node = r0 + row;
    const float c0 = coords[2*node], c1 = coords[2*node+1];
    char* shb = (char*)sAh; char* slb = (char*)sAl;
    const int swz = (row & 7) << 4;
    float e1 = 0.f, e2 = 0.f;
    #pragma unroll
    for (int i = 0; i < 8; ++i){
        const int ch = g + i*4, k0 = ch*4;
        float4 wa0 = *(const float4*)&w0[k0];
        float4 wb0 = *(const float4*)&w0[DIM + k0];
        float4 bq  = *(const float4*)&b0v[k0];
        float4 v;
        v.x = fmaf(c0, wa0.x, fmaf(c1, wb0.x, bq.x)); v.x = v.x > 0.f ? v.x : 0.f;
        v.y = fmaf(c0, wa0.y, fmaf(c1, wb0.y, bq.y)); v.y = v.y > 0.f ? v.y : 0.f;
        v.z = fmaf(c0, wa0.z, fmaf(c1, wb0.z, bq.z)); v.z = v.z > 0.f ? v.z : 0.f;
        v.w = fmaf(c0, wa0.w, fmaf(c1, wb0.w, bq.w)); v.w = v.w > 0.f ? v.w : 0.f;
        float4 q1 = *(const float4*)&u12[k0];
        float4 q2 = *(const float4*)&u12[128 + k0];
        e1 = fmaf(v.x,q1.x, fmaf(v.y,q1.y, fmaf(v.z,q1.z, fmaf(v.w,q1.w, e1))));
        e2 = fmaf(v.x,q2.x, fmaf(v.y,q2.y, fmaf(v.z,q2.z, fmaf(v.w,q2.w, e2))));
        ushort4 hq, lq;
        hq.x = f2bf(v.x); lq.x = f2bf(v.x - bf2f(hq.x));
        hq.y = f2bf(v.y); lq.y = f2bf(v.y - bf2f(hq.y));
        hq.z = f2bf(v.z); lq.z = f2bf(v.z - bf2f(hq.z));
        hq.w = f2bf(v.w); lq.w = f2bf(v.w - bf2f(hq.w));
        const int bo = (ch*8) ^ swz;
        *(ushort4*)(shb + row*256 + bo) = hq;
        *(ushort4*)(slb + row*256 + bo) = lq;
    }
    e1 += __shfl_xor(e1, 1); e1 += __shfl_xor(e1, 2);
    e2 += __shfl_xor(e2, 1); e2 += __shfl_xor(e2, 2);
    if (g == 0){ e1p[r0 + row] = e1 + su[0]; e2p[r0 + row] = e2 + su[1]; }
    __syncthreads();
    f32x4 acc[4][2] = {};
    #pragma unroll
    for (int m = 0; m < 4; ++m){
        const int ar = m*16 + lc, asw = (ar & 7) << 4;
        #pragma unroll
        for (int kc = 0; kc < 4; ++kc){
            const int bo = (kc*64 + lk*16) ^ asw;
            bf16x8 ah = *(bf16x8*)(shb + ar*256 + bo);
            bf16x8 al = *(bf16x8*)(slb + ar*256 + bo);
            #pragma unroll
            for (int cg = 0; cg < 2; ++cg){
                acc[m][cg] = __builtin_amdgcn_mfma_f32_16x16x32_bf16(ah, bh[cg][kc], acc[m][cg], 0, 0, 0);
                acc[m][cg] = __builtin_amdgcn_mfma_f32_16x16x32_bf16(ah, bl[cg][kc], acc[m][cg], 0, 0, 0);
                acc[m][cg] = __builtin_amdgcn_mfma_f32_16x16x32_bf16(al, bh[cg][kc], acc[m][cg], 0, 0, 0);
            }
        }
    }
    #pragma unroll
    for (int m = 0; m < 4; ++m){
        const int rg = r0 + m*16 + lk*4;
        #pragma unroll
        for (int cg = 0; cg < 2; ++cg){
            const int col = wv*32 + cg*16 + lc;
            const float bb = bfuse[col];
            #pragma unroll
            for (int j = 0; j < 4; ++j) Wh[(size_t)(rg+j)*DIM + col] = acc[m][cg][j] + bb;
        }
    }
}

// ------------- GAT GEMM (layers 1,2): Wh = h @ W + e1/e2 via h@(W@a) ---------------
__global__ __launch_bounds__(256) void gatmfma_k(const float* __restrict__ A,
    const unsigned short* __restrict__ pk, const float* __restrict__ wa,
    float* __restrict__ Wh, float* __restrict__ e1p, float* __restrict__ e2p)
{
    __shared__ unsigned short sAh[64*128], sAl[64*128];
    const int t = threadIdx.x, r0 = blockIdx.x*64;
    const int wv = t >> 6, l = t & 63, lc = l & 15, lk = l >> 4;
    const unsigned short* ph = pk;
    const unsigned short* pl = pk + 16384;
    bf16x8 bh[2][4], bl[2][4];
    #pragma unroll
    for (int cg = 0; cg < 2; ++cg){
        const int col = wv*32 + cg*16 + lc;
        #pragma unroll
        for (int kc = 0; kc < 4; ++kc){
            const int k0 = kc*32 + lk*8;
            bh[cg][kc] = *(const bf16x8*)&ph[col*128 + k0];
            bl[cg][kc] = *(const bf16x8*)&pl[col*128 + k0];
        }
    }
    const int row = t >> 2, g = t & 3;
    const float* Ar = A + (size_t)(r0 + row)*DIM;
    char* shb = (char*)sAh; char* slb = (char*)sAl;
    const int swz = (row & 7) << 4;
    float e1 = 0.f, e2 = 0.f;
    #pragma unroll
    for (int i = 0; i < 8; ++i){
        const int ch = g + i*4;
        float4 a  = *(const float4*)&Ar[ch*4];
        float4 u1 = *(const float4*)&wa[ch*4];
        float4 u2 = *(const float4*)&wa[128 + ch*4];
        e1 = fmaf(a.x,u1.x, fmaf(a.y,u1.y, fmaf(a.z,u1.z, fmaf(a.w,u1.w, e1))));
        e2 = fmaf(a.x,u2.x, fmaf(a.y,u2.y, fmaf(a.z,u2.z, fmaf(a.w,u2.w, e2))));
        ushort4 hq, lq;
        hq.x = f2bf(a.x); lq.x = f2bf(a.x - bf2f(hq.x));
        hq.y = f2bf(a.y); lq.y = f2bf(a.y - bf2f(hq.y));
        hq.z = f2bf(a.z); lq.z = f2bf(a.z - bf2f(hq.z));
        hq.w = f2bf(a.w); lq.w = f2bf(a.w - bf2f(hq.w));
        const int bo = (ch*8) ^ swz;
        *(ushort4*)(shb + row*256 + bo) = hq;
        *(ushort4*)(slb + row*256 + bo) = lq;
    }
    e1 += __shfl_xor(e1, 1); e1 += __shfl_xor(e1, 2);
    e2 += __shfl_xor(e2, 1); e2 += __shfl_xor(e2, 2);
    if (g == 0){ e1p[r0 + row] = e1; e2p[r0 + row] = e2; }
    __syncthreads();
    f32x4 acc[4][2] = {};
    #pragma unroll
    for (int m = 0; m < 4; ++m){
        const int ar = m*16 + lc, asw = (ar & 7) << 4;
        #pragma unroll
        for (int kc = 0; kc < 4; ++kc){
            const int bo = (kc*64 + lk*16) ^ asw;
            bf16x8 ah = *(bf16x8*)(shb + ar*256 + bo);
            bf16x8 al = *(bf16x8*)(slb + ar*256 + bo);
            #pragma unroll
            for (int cg = 0; cg < 2; ++cg){
                acc[m][cg] = __builtin_amdgcn_mfma_f32_16x16x32_bf16(ah, bh[cg][kc], acc[m][cg], 0, 0, 0);
                acc[m][cg] = __builtin_amdgcn_mfma_f32_16x16x32_bf16(ah, bl[cg][kc], acc[m][cg], 0, 0, 0);
                acc[m][cg] = __builtin_amdgcn_mfma_f32_16x16x32_bf16(al, bh[cg][kc], acc[m][cg], 0, 0, 0);
            }
        }
    }
    #pragma unroll
    for (int m = 0; m < 4; ++m){
        const int rg = r0 + m*16 + lk*4;
        #pragma unroll
        for (int cg = 0; cg < 2; ++cg){
            const int col = wv*32 + cg*16 + lc;
            #pragma unroll
            for (int j = 0; j < 4; ++j) Wh[(size_t)(rg+j)*DIM + col] = acc[m][cg][j];
        }
    }
}

// ------------- final projection GEMM (split-bf16 MFMA), output dtype per flag ------
__global__ __launch_bounds__(256) void projmfma_k(const float* __restrict__ A,
    const unsigned short* __restrict__ pk, const float* __restrict__ bias,
    void* __restrict__ outp, const float* __restrict__ flag)
{
    __shared__ unsigned short sAh[64*128], sAl[64*128];
    const int t = threadIdx.x, r0 = blockIdx.x*64;
    const int wv = t >> 6, l = t & 63, lc = l & 15, lk = l >> 4;
    const unsigned short* ph = pk;
    const unsigned short* pl = pk + 8192;
    bf16x8 bh[4], bl[4];
    const int col = wv*16 + lc;
    #pragma unroll
    for (int kc = 0; kc < 4; ++kc){
        const int k0 = kc*32 + lk*8;
        bh[kc] = *(const bf16x8*)&ph[col*128 + k0];
        bl[kc] = *(const bf16x8*)&pl[col*128 + k0];
    }
    const int row = t >> 2, g = t & 3;
    const float* Ar = A + (size_t)(r0 + row)*DIM;
    char* shb = (char*)sAh; char* slb = (char*)sAl;
    const int swz = (row & 7) << 4;
    #pragma unroll
    for (int i = 0; i < 8; ++i){
        const int ch = g + i*4;
        float4 a = *(const float4*)&Ar[ch*4];
        ushort4 hq, lq;
        hq.x = f2bf(a.x); lq.x = f2bf(a.x - bf2f(hq.x));
        hq.y = f2bf(a.y); lq.y = f2bf(a.y - bf2f(hq.y));
        hq.z = f2bf(a.z); lq.z = f2bf(a.z - bf2f(hq.z));
        hq.w = f2bf(a.w); lq.w = f2bf(a.w - bf2f(hq.w));
        const int bo = (ch*8) ^ swz;
        *(ushort4*)(shb + row*256 + bo) = hq;
        *(ushort4*)(slb + row*256 + bo) = lq;
    }
    __syncthreads();
    f32x4 acc[4] = {};
    #pragma unroll
    for (int m = 0; m < 4; ++m){
        const int ar = m*16 + lc, asw = (ar & 7) << 4;
        #pragma unroll
        for (int kc = 0; kc < 4; ++kc){
            const int bo = (kc*64 + lk*16) ^ asw;
            bf16x8 ah = *(bf16x8*)(shb + ar*256 + bo);
            bf16x8 al = *(bf16x8*)(slb + ar*256 + bo);
            acc[m] = __builtin_amdgcn_mfma_f32_16x16x32_bf16(ah, bh[kc], acc[m], 0, 0, 0);
            acc[m] = __builtin_amdgcn_mfma_f32_16x16x32_bf16(ah, bl[kc], acc[m], 0, 0, 0);
            acc[m] = __builtin_amdgcn_mfma_f32_16x16x32_bf16(al, bh[kc], acc[m], 0, 0, 0);
        }
    }
    const float bb = bias[col];
    const bool isbf = (flag[0] != 0.0f);
    #pragma unroll
    for (int m = 0; m < 4; ++m){
        const int rg = r0 + m*16 + lk*4;
        #pragma unroll
        for (int j = 0; j < 4; ++j){
            float v = acc[m][j] + bb;
            size_t p = (size_t)(rg+j)*ODIM + col;
            if (isbf) ((bf16*)outp)[p] = __float2bfloat16(v);
            else      ((float*)outp)[p] = v;
        }
    }
}

// ------------- per-batch bitonic sort, u64-packed key (val<<32 | idx) --------------
// Packing halves LDS instruction count vs separate v[]/ix[] arrays and makes the
// compare-exchange a single u64 compare. Wave-local stages (stride<=64) need only a
// compiler fence (wave64 lockstep); barriers only for stride>=128.
#define WAVE_FENCE() __asm__ volatile("" ::: "memory")
__global__ void sort_k(const float* __restrict__ e2p, float* __restrict__ e2s, int* __restrict__ sidx,
                       float* __restrict__ wp, float* __restrict__ wn, float* __restrict__ e2m)
{
    __shared__ unsigned long long kv[2048];
    const int b = blockIdx.x, t = threadIdx.x;   // 1024 threads
    for (int i = t; i < 2048; i += 1024)
        kv[i] = (i < NNODE) ? (((unsigned long long)ordu(e2p[b*NNODE + i]) << 32) | (unsigned)i)
                            : 0xFFFFFFFFFFFFFFFFull;
    __syncthreads();

    // sizes 2..128: all strides <= 64 -> fully wave-local, no block barriers
    #pragma unroll 1
    for (int size = 2; size <= 128; size <<= 1){
        #pragma unroll 1
        for (int stride = size >> 1; stride > 0; stride >>= 1){
            int i = 2*t - (t & (stride-1));
            int j = i + stride;
            bool asc = ((i & size) == 0);
            unsigned long long ki = kv[i], kj = kv[j];
            bool sw = asc ? (ki > kj) : (ki < kj);
            if (sw){ kv[i] = kj; kv[j] = ki; }
            WAVE_FENCE();
        }
    }
    __syncthreads();

    // sizes 256..2048: strides >=128 need block barriers; strides <=64 wave-local
    #pragma unroll 1
    for (int size = 256; size <= 2048; size <<= 1){
        #pragma unroll 1
        for (int stride = size >> 1; stride >= 128; stride >>= 1){
            int i = 2*t - (t & (stride-1));
            int j = i + stride;
            bool asc = ((i & size) == 0);
            unsigned long long ki = kv[i], kj = kv[j];
            bool sw = asc ? (ki > kj) : (ki < kj);
            if (sw){ kv[i] = kj; kv[j] = ki; }
            __syncthreads();
        }
        #pragma unroll 1
        for (int stride = 64; stride > 0; stride >>= 1){
            int i = 2*t - (t & (stride-1));
            int j = i + stride;
            bool asc = ((i & size) == 0);
            unsigned long long ki = kv[i], kj = kv[j];
            bool sw = asc ? (ki > kj) : (ki < kj);
            if (sw){ kv[i] = kj; kv[j] = ki; }
            WAVE_FENCE();
        }
        __syncthreads();
    }

    const float mx = iordu((unsigned)(kv[NNODE-1] >> 32));   // pads sort above 2000
    for (int i = t; i < NNODE; i += 1024){
        unsigned long long key = kv[i];
        float val = iordu((unsigned)(key >> 32));
        e2s [b*NNODE+i] = val;
        sidx[b*NNODE+i] = (int)(key & 0xFFFFFFFFull);
        wp  [b*NNODE+i] = __expf(val - mx);          // <= 1
        wn  [b*NNODE+i] = __expf(0.2f*(val - mx));   // <= 1
    }
    if (t == 0) e2m[b] = mx;
}

// ------------- pass A: per-chunk partial sums (vector[D] + scalar) ----------------
__global__ void passA_k(const float* __restrict__ Wh, const int* __restrict__ sidx,
    const float* __restrict__ wp, const float* __restrict__ wn,
    float* __restrict__ chunkP, float* __restrict__ chunkN,
    float* __restrict__ schunkP, float* __restrict__ schunkN)
{
    const int b = blockIdx.x / CHK, c = blockIdx.x % CHK, d = threadIdx.x;
    const int base = b*NNODE;
    float sp=0.f, sn=0.f, ssp=0.f, ssn=0.f;
    #pragma unroll 4
    for (int r = c*CKS; r < c*CKS + CKS; ++r){
        int j = sidx[base + r];
        float whv = Wh[((size_t)base + j)*DIM + d];
        float wpv = wp[base + r], wnv = wn[base + r];
        sp = fmaf(wpv, whv, sp);  sn = fmaf(wnv, whv, sn);
        ssp += wpv;  ssn += wnv;
    }
    const int idx = b*CHK + c;
    chunkP[idx*DIM + d] = sp;
    chunkN[idx*DIM + d] = sn;
    if (d == 0){ schunkP[idx] = ssp; schunkN[idx] = ssn; }
}

// ------------- pass B: cross-chunk suffix (P) / prefix (N) offsets (exclusive) -----
__global__ __launch_bounds__(256) void passB_k(
    const float* __restrict__ chunkP, const float* __restrict__ chunkN,
    const float* __restrict__ schunkP, const float* __restrict__ schunkN,
    float* __restrict__ offP, float* __restrict__ offN,
    float* __restrict__ soffP, float* __restrict__ soffN)
{
    const int b = blockIdx.x, tid = threadIdx.x;
    const bool doP = (blockIdx.y == 0);
    const float* chunk  = doP ? chunkP  : chunkN;
    const float* schunk = doP ? schunkP : schunkN;
    float* off  = doP ? offP  : offN;
    float* soff = doP ? soffP : soffN;

    if (tid < 128){
        const int d = tid;
        float acc = 0.f, v[25];
        #pragma unroll
        for (int t = 0; t < 5; ++t){
            const int c0 = doP ? (4-t)*25 : t*25;
            #pragma unroll
            for (int k = 0; k < 25; ++k) v[k] = chunk[(b*CHK + c0 + k)*DIM + d];
            if (doP){
                #pragma unroll
                for (int k = 24; k >= 0; --k){ off[(b*CHK + c0 + k)*DIM + d] = acc; acc += v[k]; }
            } else {
                #pragma unroll
                for (int k = 0; k < 25; ++k){ off[(b*CHK + c0 + k)*DIM + d] = acc; acc += v[k]; }
            }
        }
    } else if (tid == 128){
        float sacc = 0.f, sv[25];
        #pragma unroll
        for (int t = 0; t < 5; ++t){
            const int c0 = doP ? (4-t)*25 : t*25;
            #pragma unroll
            for (int k = 0; k < 25; ++k) sv[k] = schunk[b*CHK + c0 + k];
            if (doP){
                #pragma unroll
                for (int k = 24; k >= 0; --k){ soff[b*CHK + c0 + k] = sacc; sacc += sv[k]; }
            } else {
                #pragma unroll
                for (int k = 0; k < 25; ++k){ soff[b*CHK + c0 + k] = sacc; sacc += sv[k]; }
            }
        }
    }
}

// ------------- pass C: full suffix (pos) / prefix (neg) arrays over sorted order ---
__global__ void passC_k(const float* __restrict__ Wh, const int* __restrict__ sidx,
    const float* __restrict__ wp, const float* __restrict__ wn,
    const float* __restrict__ offP, const float* __restrict__ offN,
    const float* __restrict__ soffP, const float* __restrict__ soffN,
    float* __restrict__ Ppos, float* __restrict__ Pneg,
    float* __restrict__ pposs, float* __restrict__ pnegs)
{
    const int b = blockIdx.x / CHK, c = blockIdx.x % CHK, d = threadIdx.x;
    const int base = b*NNODE;
    const size_t pb = (size_t)b*NP1;
    const int idx = b*CHK + c;
    const int r0 = c*CKS, r1 = r0 + CKS;

    if (c == CHK-1){
        Ppos[(pb + NNODE)*DIM + d] = 0.f;
        if (d == 0) pposs[pb + NNODE] = 0.f;
    }
    float pr = offP[idx*DIM + d], spr = soffP[idx];
    for (int r = r1-1; r >= r0; --r){
        int j = sidx[base + r];
        float whv = Wh[((size_t)base + j)*DIM + d];
        float wpv = wp[base + r];
        pr  = fmaf(wpv, whv, pr);
        spr += wpv;
        Ppos[(pb + r)*DIM + d] = pr;
        if (d == 0) pposs[pb + r] = spr;
    }
    float nr = offN[idx*DIM + d], snr = soffN[idx];
    for (int r = r0; r < r1; ++r){
        int j = sidx[base + r];
        float whv = Wh[((size_t)base + j)*DIM + d];
        float wnv = wn[base + r];
        Pneg[(pb + r)*DIM + d] = nr;
        if (d == 0) pnegs[pb + r] = snr;
        nr  = fmaf(wnv, whv, nr);
        snr += wnv;
    }
    if (c == CHK-1){
        Pneg[(pb + NNODE)*DIM + d] = nr;
        if (d == 0) pnegs[pb + NNODE] = snr;
    }
}

// ------------- output, 16 rows per block: parallel binsearch then stream -----------
__global__ __launch_bounds__(128) void out16_k(const float* __restrict__ e1p,
    const float* __restrict__ e2s, const float* __restrict__ e2m,
    const float* __restrict__ Ppos, const float* __restrict__ Pneg,
    const float* __restrict__ pposs, const float* __restrict__ pnegs, float* __restrict__ h)
{
    __shared__ int   slo[CKS];
    __shared__ float sps[CKS], sns[CKS];
    const int b = blockIdx.x / CHK, c = blockIdx.x % CHK, d = threadIdx.x;
    const int base = b*NNODE, r0 = c*CKS;
    const size_t pb = (size_t)b*NP1;

    if (d < CKS){
        int row = base + r0 + d;
        float e1v = e1p[row];
        float s = e1v + e2m[b];
        float m = (s >= 0.f) ? s : 0.2f*s;
        sps[d] = __expf(s - m);
        sns[d] = __expf(0.2f*s - m);
        const float* es = e2s + base;
        float tt = -e1v;
        int lo = 0, hi = NNODE;
        while (lo < hi){ int mid = (lo+hi) >> 1; if (es[mid] < tt) lo = mid+1; else hi = mid; }
        slo[d] = lo;
    }
    __syncthreads();
    #pragma unroll 4
    for (int k = 0; k < CKS; ++k){
        int row = base + r0 + k;
        size_t kb = pb + slo[k];
        float numer = sps[k]*Ppos[kb*DIM + d] + sns[k]*Pneg[kb*DIM + d];
        float Z     = sps[k]*pposs[kb]        + sns[k]*pnegs[kb];
        float q = numer / Z;
        h[(size_t)row*DIM + d] = (q > 0.f) ? q : ((q == q) ? 0.f : q);
    }
}

extern "C" void kernel_launch(void* const* d_in, const int* in_sizes, int n_in,
                              void* d_out, int out_size, void* d_ws, size_t ws_size,
                              hipStream_t stream)
{
    (void)in_sizes; (void)n_in; (void)out_size; (void)ws_size;

    float* f = (float*)d_ws;
    float* flag    = f;  f += 4;
    float* cvt     = f;  f += CVT_TOT;                 // 0.56 MB
    float* h       = f;  f += (size_t)BN*DIM;          // 16.4 MB
    float* Wh      = f;  f += (size_t)BN*DIM;          // 16.4 MB
    float* Ppos    = f;  f += (size_t)BATCH*NP1*DIM;   // 16.4 MB
    float* Pneg    = f;  f += (size_t)BATCH*NP1*DIM;   // 16.4 MB
    float* chunkP  = f;  f += BATCH*CHK*DIM;           // 1 MB
    float* chunkN  = f;  f += BATCH*CHK*DIM;           // 1 MB
    float* offP    = f;  f += BATCH*CHK*DIM;           // 1 MB
    float* offN    = f;  f += BATCH*CHK*DIM;           // 1 MB
    float* schunkP = f;  f += BATCH*CHK;
    float* schunkN = f;  f += BATCH*CHK;
    float* soffP   = f;  f += BATCH*CHK;
    float* soffN   = f;  f += BATCH*CHK;
    float* e1p     = f;  f += BN;                      // full e1
    float* e2p     = f;  f += BN;                      // full e2
    float* e2s     = f;  f += BN;
    float* wp      = f;  f += BN;
    float* wn      = f;  f += BN;
    float* pposs   = f;  f += BATCH*NP1;
    float* pnegs   = f;  f += BATCH*NP1;
    float* e2m     = f;  f += 16;
    int*   sidx    = (int*)f;
    unsigned short* pk = (unsigned short*)(sidx + BN);   // 16B-aligned (all counts %4==0)
    float* wa      = (float*)(pk + PK_TOT);              // 3 layers x {wa1,wa2}[128]
    float* u12     = wa + 768;                           // u1[128], u2[128]
    float* bfuse   = u12 + 256;                          // b1@W0 [128]
    float* su      = bfuse + 128;                        // s1, s2

    // 1. convert all inputs to fp32 (sniff embedded)
    InPtrs ip;
    for (int i = 0; i < 10; ++i) ip.p[i] = d_in[i];
    convert_all_k<<<(CVT_TOT+255)/256, 256, 0, stream>>>(ip, cvt, flag);

    // 2. pack W layers 1,2 + proj; wa = W@a.  3. fused-encoder weights for layer 0.
    prep_k<<<4, 256, 0, stream>>>(cvt, pk, wa);
    prep2_k<<<130, 128, 0, stream>>>(cvt, pk, wa, u12, bfuse, su);

    // 4. GAT layers (exact separable-softmax factorization); layer 0 folds encoder
    for (int l = 0; l < NLAYER; ++l){
        if (l == 0)
            gat0mfma_k<<<BN/64, 256, 0, stream>>>(cvt, pk + PK_GAT(0), u12, su, bfuse,
                                                  Wh, e1p, e2p);
        else
            gatmfma_k<<<BN/64, 256, 0, stream>>>(h, pk + PK_GAT(l), wa + l*256, Wh, e1p, e2p);
        sort_k<<<BATCH, 1024, 0, stream>>>(e2p, e2s, sidx, wp, wn, e2m);
        passA_k<<<BATCH*CHK, DIM, 0, stream>>>(Wh, sidx, wp, wn, chunkP, chunkN, schunkP, schunkN);
        passB_k<<<dim3(BATCH, 2), 256, 0, stream>>>(chunkP, chunkN, schunkP, schunkN,
                                                    offP, offN, soffP, soffN);
        passC_k<<<BATCH*CHK, DIM, 0, stream>>>(Wh, sidx, wp, wn, offP, offN, soffP, soffN,
                                               Ppos, Pneg, pposs, pnegs);
        out16_k<<<BATCH*CHK, DIM, 0, stream>>>(e1p, e2s, e2m, Ppos, Pneg, pposs, pnegs, h);
    }

    // 5. projection (split-bf16 MFMA), output dtype per flag
    projmfma_k<<<BN/64, 256, 0, stream>>>(h, pk + PK_PROJ, cvt + OFF_PB, d_out, flag);
}

// Round 5
// 294.837 us; speedup vs baseline: 1.2322x; 1.0239x over previous
//
#include <hip/hip_runtime.h>
#include <hip/hip_bf16.h>

using bf16 = __hip_bfloat16;

#define BATCH 16
#define NNODE 2000
#define DIM   128
#define ODIM  64
#define NLAYER 3
#define BN    (BATCH*NNODE)   // 32000
#define NP1   (NNODE+1)       // 2001
#define CHK   125             // chunks per batch
#define CKS   16              // chunk size (125*16 = 2000)

// converted-input element offsets inside cvt buffer
#define OFF_COORDS 0
#define OFF_EW0    64000
#define OFF_EB0    64256
#define OFF_EW1    64384
#define OFF_EB1    80768
#define OFF_GW     80896
#define OFF_GA1    130048
#define OFF_GA2    130432
#define OFF_PW     130816
#define OFF_PB     139008
#define CVT_TOT    139072

// packed-weight offsets (ushort elements): [col][k] fragment order, hi plane then lo plane
// layer-0 slot holds Wfuse = enc_w1 @ gat_W[0] (encoder folded in)
#define PK_GAT(l)  (32768 + (l)*32768)     // 2*16384 each
#define PK_PROJ    131072                  // 2*8192
#define PK_TOT     147456

typedef __attribute__((ext_vector_type(8))) short bf16x8;
typedef __attribute__((ext_vector_type(4))) float f32x4;

__device__ __forceinline__ unsigned short f2bf(float f){
    union { float f; unsigned u; } x; x.f = f;
    unsigned r = (x.u + 0x7FFFu + ((x.u >> 16) & 1u)) >> 16;
    return (unsigned short)r;
}
__device__ __forceinline__ float bf2f(unsigned short h){
    union { unsigned u; float f; } x; x.u = ((unsigned)h) << 16;
    return x.f;
}
// monotone float -> uint transform (total order) and inverse
__device__ __forceinline__ unsigned ordu(float f){
    union { float f; unsigned u; } x; x.f = f;
    return (x.u & 0x80000000u) ? ~x.u : (x.u | 0x80000000u);
}
__device__ __forceinline__ float iordu(unsigned u){
    union { unsigned u; float f; } x;
    x.u = (u & 0x80000000u) ? (u ^ 0x80000000u) : ~u;
    return x.f;
}

struct InPtrs { const void* p[10]; };

// ------------- convert ALL inputs to fp32 (sniff embedded per block) ---------------
__global__ void convert_all_k(InPtrs in, float* __restrict__ dst, float* __restrict__ flag)
{
    __shared__ int scnt[256];
    const unsigned short* raw = (const unsigned short*)in.p[0];
    int t = threadIdx.x, c = 0;
    for (int k = t; k < 2048; k += 256){
        unsigned short u = raw[2*k];                 // first 8 KB, safe either dtype
        int e = (u >> 7) & 0xFF;
        if (e >= 100 && e <= 140) ++c;
    }
    scnt[t] = c;
    __syncthreads();
    for (int s = 128; s; s >>= 1){ if (t < s) scnt[t] += scnt[t+s]; __syncthreads(); }
    const bool isbf16 = (scnt[0] >= 1800);
    if (blockIdx.x == 0 && t == 0) flag[0] = isbf16 ? 1.0f : 0.0f;

    const int off[11] = {OFF_COORDS,OFF_EW0,OFF_EB0,OFF_EW1,OFF_EB1,
                         OFF_GW,OFF_GA1,OFF_GA2,OFF_PW,OFF_PB,CVT_TOT};
    int i = blockIdx.x*256 + t;
    if (i >= CVT_TOT) return;
    int seg = 0;
    #pragma unroll
    for (int s = 1; s < 10; ++s) if (i >= off[s]) seg = s;
    int li = i - off[seg];
    if (isbf16) dst[i] = __bfloat162float(((const bf16*)in.p[seg])[li]);
    else        dst[i] = ((const float*)in.p[seg])[li];
}

// ------------- prep: pack W layers 1,2 + proj to bf16 hi/lo; wa = W@a vectors ------
__global__ __launch_bounds__(256) void prep_k(const float* __restrict__ cvt,
                                              unsigned short* __restrict__ pk,
                                              float* __restrict__ wa)
{
    const int mi = blockIdx.x, t = threadIdx.x;
    if (mi < 3){
        const float* W; unsigned short* dst; int N;
        if (mi == 0)      { W = cvt + OFF_GW + 1*DIM*DIM;  dst = pk + PK_GAT(1); N = 128; }
        else if (mi == 1) { W = cvt + OFF_GW + 2*DIM*DIM;  dst = pk + PK_GAT(2); N = 128; }
        else              { W = cvt + OFF_PW;              dst = pk + PK_PROJ;   N = 64;  }
        const int tot = 128*N;
        unsigned short* dh = dst;
        unsigned short* dl = dst + tot;
        for (int e = t; e < tot; e += 256){
            int col = e >> 7, k = e & 127;            // dst layout [col][k]
            float v = W[k*N + col];
            unsigned short hb = f2bf(v);
            unsigned short lb = f2bf(v - bf2f(hb));
            dh[e] = hb;
            dl[e] = lb;
        }
    } else {
        // wa[l*256 + half*128 + r] = (gat_W[l] @ a_half[l])[r]
        for (int idx = t; idx < 3*256; idx += 256){
            const int l = idx >> 8, rem = idx & 255, half = rem >> 7, r = rem & 127;
            const float* W  = cvt + OFF_GW + l*DIM*DIM;
            const float* av = cvt + (half ? OFF_GA2 : OFF_GA1) + l*DIM;
            float s = 0.f;
            for (int c2 = 0; c2 < 128; ++c2) s = fmaf(W[r*128 + c2], av[c2], s);
            wa[l*256 + half*128 + r] = s;
        }
    }
}

// ------------- prep2: Wfuse = w1@W0 (packed), bfuse = b1@W0, u1/u2, s1/s2 ----------
__global__ __launch_bounds__(128) void prep2_k(const float* __restrict__ cvt,
    unsigned short* __restrict__ pk, const float* __restrict__ wa,
    float* __restrict__ u12, float* __restrict__ bfuse, float* __restrict__ su)
{
    const int b = blockIdx.x, t = threadIdx.x;
    const float* w1 = cvt + OFF_EW1;
    const float* W0 = cvt + OFF_GW;
    if (b < 128){
        float acc = 0.f;
        for (int d = 0; d < 128; ++d) acc = fmaf(w1[b*DIM + d], W0[d*DIM + t], acc);
        unsigned short hb = f2bf(acc), lb = f2bf(acc - bf2f(hb));
        unsigned short* dst = pk + PK_GAT(0);
        dst[t*128 + b]         = hb;      // [col=t][k=b] hi plane
        dst[16384 + t*128 + b] = lb;      // lo plane
    } else if (b == 128){
        const float* b1 = cvt + OFF_EB1;
        float acc = 0.f;
        for (int d = 0; d < 128; ++d) acc = fmaf(b1[d], W0[d*DIM + t], acc);
        bfuse[t] = acc;
        if (t < 2){
            float s = 0.f;
            for (int d = 0; d < 128; ++d) s = fmaf(b1[d], wa[t*128 + d], s);
            su[t] = s;
        }
    } else {
        float a1 = 0.f, a2 = 0.f;
        for (int d = 0; d < 128; ++d){
            float w = w1[t*DIM + d];
            a1 = fmaf(w, wa[d],       a1);
            a2 = fmaf(w, wa[128 + d], a2);
        }
        u12[t]       = a1;
        u12[128 + t] = a2;
    }
}

// ---- shared MFMA convention: A tile 64x128 staged as hi/lo bf16, XOR-swizzled -----
// LDS row stride 256 B; swizzle: byte_in_row ^= (row&7)<<4  (both write & read sides)

// ------------- layer-0 GAT: encoder folded in. A1 = relu(coords@w0+b0) inline ------
__global__ __launch_bounds__(256) void gat0mfma_k(const float* __restrict__ cvt,
    const unsigned short* __restrict__ pk, const float* __restrict__ u12,
    const float* __restrict__ su, const float* __restrict__ bfuse,
    float* __restrict__ Wh, float* __restrict__ e1p, float* __restrict__ e2p)
{
    __shared__ unsigned short sAh[64*128], sAl[64*128];
    const int t = threadIdx.x, r0 = blockIdx.x*64;
    const int wv = t >> 6, l = t & 63, lc = l & 15, lk = l >> 4;
    const unsigned short* ph = pk;
    const unsigned short* pl = pk + 16384;
    bf16x8 bh[2][4], bl[2][4];
    #pragma unroll
    for (int cg = 0; cg < 2; ++cg){
        const int col = wv*32 + cg*16 + lc;
        #pragma unroll
        for (int kc = 0; kc < 4; ++kc){
            const int k0 = kc*32 + lk*8;
            bh[cg][kc] = *(const bf16x8*)&ph[col*128 + k0];
            bl[cg][kc] = *(const bf16x8*)&pl[col*128 + k0];
        }
    }
    const int row = t >> 2, g = t & 3;
    const float* coords = cvt + OFF_COORDS;
    const float* w0  = cvt + OFF_EW0;
    const float* b0v = cvt + OFF_EB0;
    const int node = r0 + row;
    const float c0 = coords[2*node], c1 = coords[2*node+1];
    char* shb = (char*)sAh; char* slb = (char*)sAl;
    const int swz = (row & 7) << 4;
    float e1 = 0.f, e2 = 0.f;
    #pragma unroll
    for (int i = 0; i < 8; ++i){
        const int ch = g + i*4, k0 = ch*4;
        float4 wa0 = *(const float4*)&w0[k0];
        float4 wb0 = *(const float4*)&w0[DIM + k0];
        float4 bq  = *(const float4*)&b0v[k0];
        float4 v;
        v.x = fmaf(c0, wa0.x, fmaf(c1, wb0.x, bq.x)); v.x = v.x > 0.f ? v.x : 0.f;
        v.y = fmaf(c0, wa0.y, fmaf(c1, wb0.y, bq.y)); v.y = v.y > 0.f ? v.y : 0.f;
        v.z = fmaf(c0, wa0.z, fmaf(c1, wb0.z, bq.z)); v.z = v.z > 0.f ? v.z : 0.f;
        v.w = fmaf(c0, wa0.w, fmaf(c1, wb0.w, bq.w)); v.w = v.w > 0.f ? v.w : 0.f;
        float4 q1 = *(const float4*)&u12[k0];
        float4 q2 = *(const float4*)&u12[128 + k0];
        e1 = fmaf(v.x,q1.x, fmaf(v.y,q1.y, fmaf(v.z,q1.z, fmaf(v.w,q1.w, e1))));
        e2 = fmaf(v.x,q2.x, fmaf(v.y,q2.y, fmaf(v.z,q2.z, fmaf(v.w,q2.w, e2))));
        ushort4 hq, lq;
        hq.x = f2bf(v.x); lq.x = f2bf(v.x - bf2f(hq.x));
        hq.y = f2bf(v.y); lq.y = f2bf(v.y - bf2f(hq.y));
        hq.z = f2bf(v.z); lq.z = f2bf(v.z - bf2f(hq.z));
        hq.w = f2bf(v.w); lq.w = f2bf(v.w - bf2f(hq.w));
        const int bo = (ch*8) ^ swz;
        *(ushort4*)(shb + row*256 + bo) = hq;
        *(ushort4*)(slb + row*256 + bo) = lq;
    }
    e1 += __shfl_xor(e1, 1); e1 += __shfl_xor(e1, 2);
    e2 += __shfl_xor(e2, 1); e2 += __shfl_xor(e2, 2);
    if (g == 0){ e1p[r0 + row] = e1 + su[0]; e2p[r0 + row] = e2 + su[1]; }
    __syncthreads();
    f32x4 acc[4][2] = {};
    #pragma unroll
    for (int m = 0; m < 4; ++m){
        const int ar = m*16 + lc, asw = (ar & 7) << 4;
        #pragma unroll
        for (int kc = 0; kc < 4; ++kc){
            const int bo = (kc*64 + lk*16) ^ asw;
            bf16x8 ah = *(bf16x8*)(shb + ar*256 + bo);
            bf16x8 al = *(bf16x8*)(slb + ar*256 + bo);
            #pragma unroll
            for (int cg = 0; cg < 2; ++cg){
                acc[m][cg] = __builtin_amdgcn_mfma_f32_16x16x32_bf16(ah, bh[cg][kc], acc[m][cg], 0, 0, 0);
                acc[m][cg] = __builtin_amdgcn_mfma_f32_16x16x32_bf16(ah, bl[cg][kc], acc[m][cg], 0, 0, 0);
                acc[m][cg] = __builtin_amdgcn_mfma_f32_16x16x32_bf16(al, bh[cg][kc], acc[m][cg], 0, 0, 0);
            }
        }
    }
    #pragma unroll
    for (int m = 0; m < 4; ++m){
        const int rg = r0 + m*16 + lk*4;
        #pragma unroll
        for (int cg = 0; cg < 2; ++cg){
            const int col = wv*32 + cg*16 + lc;
            const float bb = bfuse[col];
            #pragma unroll
            for (int j = 0; j < 4; ++j) Wh[(size_t)(rg+j)*DIM + col] = acc[m][cg][j] + bb;
        }
    }
}

// ------------- GAT GEMM (layers 1,2): Wh = h @ W + e1/e2 via h@(W@a) ---------------
__global__ __launch_bounds__(256) void gatmfma_k(const float* __restrict__ A,
    const unsigned short* __restrict__ pk, const float* __restrict__ wa,
    float* __restrict__ Wh, float* __restrict__ e1p, float* __restrict__ e2p)
{
    __shared__ unsigned short sAh[64*128], sAl[64*128];
    const int t = threadIdx.x, r0 = blockIdx.x*64;
    const int wv = t >> 6, l = t & 63, lc = l & 15, lk = l >> 4;
    const unsigned short* ph = pk;
    const unsigned short* pl = pk + 16384;
    bf16x8 bh[2][4], bl[2][4];
    #pragma unroll
    for (int cg = 0; cg < 2; ++cg){
        const int col = wv*32 + cg*16 + lc;
        #pragma unroll
        for (int kc = 0; kc < 4; ++kc){
            const int k0 = kc*32 + lk*8;
            bh[cg][kc] = *(const bf16x8*)&ph[col*128 + k0];
            bl[cg][kc] = *(const bf16x8*)&pl[col*128 + k0];
        }
    }
    const int row = t >> 2, g = t & 3;
    const float* Ar = A + (size_t)(r0 + row)*DIM;
    char* shb = (char*)sAh; char* slb = (char*)sAl;
    const int swz = (row & 7) << 4;
    float e1 = 0.f, e2 = 0.f;
    #pragma unroll
    for (int i = 0; i < 8; ++i){
        const int ch = g + i*4;
        float4 a  = *(const float4*)&Ar[ch*4];
        float4 u1 = *(const float4*)&wa[ch*4];
        float4 u2 = *(const float4*)&wa[128 + ch*4];
        e1 = fmaf(a.x,u1.x, fmaf(a.y,u1.y, fmaf(a.z,u1.z, fmaf(a.w,u1.w, e1))));
        e2 = fmaf(a.x,u2.x, fmaf(a.y,u2.y, fmaf(a.z,u2.z, fmaf(a.w,u2.w, e2))));
        ushort4 hq, lq;
        hq.x = f2bf(a.x); lq.x = f2bf(a.x - bf2f(hq.x));
        hq.y = f2bf(a.y); lq.y = f2bf(a.y - bf2f(hq.y));
        hq.z = f2bf(a.z); lq.z = f2bf(a.z - bf2f(hq.z));
        hq.w = f2bf(a.w); lq.w = f2bf(a.w - bf2f(hq.w));
        const int bo = (ch*8) ^ swz;
        *(ushort4*)(shb + row*256 + bo) = hq;
        *(ushort4*)(slb + row*256 + bo) = lq;
    }
    e1 += __shfl_xor(e1, 1); e1 += __shfl_xor(e1, 2);
    e2 += __shfl_xor(e2, 1); e2 += __shfl_xor(e2, 2);
    if (g == 0){ e1p[r0 + row] = e1; e2p[r0 + row] = e2; }
    __syncthreads();
    f32x4 acc[4][2] = {};
    #pragma unroll
    for (int m = 0; m < 4; ++m){
        const int ar = m*16 + lc, asw = (ar & 7) << 4;
        #pragma unroll
        for (int kc = 0; kc < 4; ++kc){
            const int bo = (kc*64 + lk*16) ^ asw;
            bf16x8 ah = *(bf16x8*)(shb + ar*256 + bo);
            bf16x8 al = *(bf16x8*)(slb + ar*256 + bo);
            #pragma unroll
            for (int cg = 0; cg < 2; ++cg){
                acc[m][cg] = __builtin_amdgcn_mfma_f32_16x16x32_bf16(ah, bh[cg][kc], acc[m][cg], 0, 0, 0);
                acc[m][cg] = __builtin_amdgcn_mfma_f32_16x16x32_bf16(ah, bl[cg][kc], acc[m][cg], 0, 0, 0);
                acc[m][cg] = __builtin_amdgcn_mfma_f32_16x16x32_bf16(al, bh[cg][kc], acc[m][cg], 0, 0, 0);
            }
        }
    }
    #pragma unroll
    for (int m = 0; m < 4; ++m){
        const int rg = r0 + m*16 + lk*4;
        #pragma unroll
        for (int cg = 0; cg < 2; ++cg){
            const int col = wv*32 + cg*16 + lc;
            #pragma unroll
            for (int j = 0; j < 4; ++j) Wh[(size_t)(rg+j)*DIM + col] = acc[m][cg][j];
        }
    }
}

// ------------- final projection GEMM (split-bf16 MFMA), output dtype per flag ------
__global__ __launch_bounds__(256) void projmfma_k(const float* __restrict__ A,
    const unsigned short* __restrict__ pk, const float* __restrict__ bias,
    void* __restrict__ outp, const float* __restrict__ flag)
{
    __shared__ unsigned short sAh[64*128], sAl[64*128];
    const int t = threadIdx.x, r0 = blockIdx.x*64;
    const int wv = t >> 6, l = t & 63, lc = l & 15, lk = l >> 4;
    const unsigned short* ph = pk;
    const unsigned short* pl = pk + 8192;
    bf16x8 bh[4], bl[4];
    const int col = wv*16 + lc;
    #pragma unroll
    for (int kc = 0; kc < 4; ++kc){
        const int k0 = kc*32 + lk*8;
        bh[kc] = *(const bf16x8*)&ph[col*128 + k0];
        bl[kc] = *(const bf16x8*)&pl[col*128 + k0];
    }
    const int row = t >> 2, g = t & 3;
    const float* Ar = A + (size_t)(r0 + row)*DIM;
    char* shb = (char*)sAh; char* slb = (char*)sAl;
    const int swz = (row & 7) << 4;
    #pragma unroll
    for (int i = 0; i < 8; ++i){
        const int ch = g + i*4;
        float4 a = *(const float4*)&Ar[ch*4];
        ushort4 hq, lq;
        hq.x = f2bf(a.x); lq.x = f2bf(a.x - bf2f(hq.x));
        hq.y = f2bf(a.y); lq.y = f2bf(a.y - bf2f(hq.y));
        hq.z = f2bf(a.z); lq.z = f2bf(a.z - bf2f(hq.z));
        hq.w = f2bf(a.w); lq.w = f2bf(a.w - bf2f(hq.w));
        const int bo = (ch*8) ^ swz;
        *(ushort4*)(shb + row*256 + bo) = hq;
        *(ushort4*)(slb + row*256 + bo) = lq;
    }
    __syncthreads();
    f32x4 acc[4] = {};
    #pragma unroll
    for (int m = 0; m < 4; ++m){
        const int ar = m*16 + lc, asw = (ar & 7) << 4;
        #pragma unroll
        for (int kc = 0; kc < 4; ++kc){
            const int bo = (kc*64 + lk*16) ^ asw;
            bf16x8 ah = *(bf16x8*)(shb + ar*256 + bo);
            bf16x8 al = *(bf16x8*)(slb + ar*256 + bo);
            acc[m] = __builtin_amdgcn_mfma_f32_16x16x32_bf16(ah, bh[kc], acc[m], 0, 0, 0);
            acc[m] = __builtin_amdgcn_mfma_f32_16x16x32_bf16(ah, bl[kc], acc[m], 0, 0, 0);
            acc[m] = __builtin_amdgcn_mfma_f32_16x16x32_bf16(al, bh[kc], acc[m], 0, 0, 0);
        }
    }
    const float bb = bias[col];
    const bool isbf = (flag[0] != 0.0f);
    #pragma unroll
    for (int m = 0; m < 4; ++m){
        const int rg = r0 + m*16 + lk*4;
        #pragma unroll
        for (int j = 0; j < 4; ++j){
            float v = acc[m][j] + bb;
            size_t p = (size_t)(rg+j)*ODIM + col;
            if (isbf) ((bf16*)outp)[p] = __float2bfloat16(v);
            else      ((float*)outp)[p] = v;
        }
    }
}

// ------------- per-batch bitonic sort, u64-packed key (val<<32 | idx) --------------
#define WAVE_FENCE() __asm__ volatile("" ::: "memory")
__global__ void sort_k(const float* __restrict__ e2p, float* __restrict__ e2s, int* __restrict__ sidx,
                       float* __restrict__ wp, float* __restrict__ wn, float* __restrict__ e2m)
{
    __shared__ unsigned long long kv[2048];
    const int b = blockIdx.x, t = threadIdx.x;   // 1024 threads
    for (int i = t; i < 2048; i += 1024)
        kv[i] = (i < NNODE) ? (((unsigned long long)ordu(e2p[b*NNODE + i]) << 32) | (unsigned)i)
                            : 0xFFFFFFFFFFFFFFFFull;
    __syncthreads();

    // sizes 2..128: all strides <= 64 -> fully wave-local, no block barriers
    #pragma unroll 1
    for (int size = 2; size <= 128; size <<= 1){
        #pragma unroll 1
        for (int stride = size >> 1; stride > 0; stride >>= 1){
            int i = 2*t - (t & (stride-1));
            int j = i + stride;
            bool asc = ((i & size) == 0);
            unsigned long long ki = kv[i], kj = kv[j];
            bool sw = asc ? (ki > kj) : (ki < kj);
            if (sw){ kv[i] = kj; kv[j] = ki; }
            WAVE_FENCE();
        }
    }
    __syncthreads();

    // sizes 256..2048: strides >=128 need block barriers; strides <=64 wave-local
    #pragma unroll 1
    for (int size = 256; size <= 2048; size <<= 1){
        #pragma unroll 1
        for (int stride = size >> 1; stride >= 128; stride >>= 1){
            int i = 2*t - (t & (stride-1));
            int j = i + stride;
            bool asc = ((i & size) == 0);
            unsigned long long ki = kv[i], kj = kv[j];
            bool sw = asc ? (ki > kj) : (ki < kj);
            if (sw){ kv[i] = kj; kv[j] = ki; }
            __syncthreads();
        }
        #pragma unroll 1
        for (int stride = 64; stride > 0; stride >>= 1){
            int i = 2*t - (t & (stride-1));
            int j = i + stride;
            bool asc = ((i & size) == 0);
            unsigned long long ki = kv[i], kj = kv[j];
            bool sw = asc ? (ki > kj) : (ki < kj);
            if (sw){ kv[i] = kj; kv[j] = ki; }
            WAVE_FENCE();
        }
        __syncthreads();
    }

    const float mx = iordu((unsigned)(kv[NNODE-1] >> 32));   // pads sort above 2000
    for (int i = t; i < NNODE; i += 1024){
        unsigned long long key = kv[i];
        float val = iordu((unsigned)(key >> 32));
        e2s [b*NNODE+i] = val;
        sidx[b*NNODE+i] = (int)(key & 0xFFFFFFFFull);
        wp  [b*NNODE+i] = __expf(val - mx);          // <= 1
        wn  [b*NNODE+i] = __expf(0.2f*(val - mx));   // <= 1
    }
    if (t == 0) e2m[b] = mx;
}

// ------------- pass AC: chunk-LOCAL suffix (pos) / prefix (neg) + chunk totals -----
// Replaces old passA+passC: ONE Wh gather. localP[r] = within-chunk suffix from r
// (zero-based); localN[r] = within-chunk exclusive prefix. Chunk totals feed passB;
// out16f adds the cross-chunk offset itself.
__global__ void passAC_k(const float* __restrict__ Wh, const int* __restrict__ sidx,
    const float* __restrict__ wp, const float* __restrict__ wn,
    float* __restrict__ localP, float* __restrict__ localN,
    float* __restrict__ lposs, float* __restrict__ lnegs,
    float* __restrict__ chunkP, float* __restrict__ chunkN,
    float* __restrict__ schunkP, float* __restrict__ schunkN)
{
    const int b = blockIdx.x / CHK, c = blockIdx.x % CHK, d = threadIdx.x;
    const int base = b*NNODE;
    const size_t pb = (size_t)b*NP1;
    const int idx = b*CHK + c;
    const int r0 = c*CKS, r1 = r0 + CKS;

    if (c == CHK-1){
        localP[(pb + NNODE)*DIM + d] = 0.f;
        if (d == 0) lposs[pb + NNODE] = 0.f;
    }
    float pr = 0.f, spr = 0.f;                        // suffix, zero-based
    for (int r = r1-1; r >= r0; --r){
        int j = sidx[base + r];
        float whv = Wh[((size_t)base + j)*DIM + d];
        float wpv = wp[base + r];
        pr  = fmaf(wpv, whv, pr);
        spr += wpv;
        localP[(pb + r)*DIM + d] = pr;
        if (d == 0) lposs[pb + r] = spr;
    }
    chunkP[idx*DIM + d] = pr;
    if (d == 0) schunkP[idx] = spr;

    float nr = 0.f, snr = 0.f;                        // exclusive prefix, zero-based
    for (int r = r0; r < r1; ++r){
        int j = sidx[base + r];
        float whv = Wh[((size_t)base + j)*DIM + d];
        float wnv = wn[base + r];
        localN[(pb + r)*DIM + d] = nr;
        if (d == 0) lnegs[pb + r] = snr;
        nr  = fmaf(wnv, whv, nr);
        snr += wnv;
    }
    if (c == CHK-1){
        localN[(pb + NNODE)*DIM + d] = nr;            // full last-chunk prefix
        if (d == 0) lnegs[pb + NNODE] = snr;
    }
    chunkN[idx*DIM + d] = nr;
    if (d == 0) schunkN[idx] = snr;
}

// ------------- pass B: cross-chunk suffix (P) / prefix (N) offsets (exclusive) -----
__global__ __launch_bounds__(256) void passB_k(
    const float* __restrict__ chunkP, const float* __restrict__ chunkN,
    const float* __restrict__ schunkP, const float* __restrict__ schunkN,
    float* __restrict__ offP, float* __restrict__ offN,
    float* __restrict__ soffP, float* __restrict__ soffN)
{
    const int b = blockIdx.x, tid = threadIdx.x;
    const bool doP = (blockIdx.y == 0);
    const float* chunk  = doP ? chunkP  : chunkN;
    const float* schunk = doP ? schunkP : schunkN;
    float* off  = doP ? offP  : offN;
    float* soff = doP ? soffP : soffN;

    if (tid < 128){
        const int d = tid;
        float acc = 0.f, v[25];
        #pragma unroll
        for (int t = 0; t < 5; ++t){
            const int c0 = doP ? (4-t)*25 : t*25;
            #pragma unroll
            for (int k = 0; k < 25; ++k) v[k] = chunk[(b*CHK + c0 + k)*DIM + d];
            if (doP){
                #pragma unroll
                for (int k = 24; k >= 0; --k){ off[(b*CHK + c0 + k)*DIM + d] = acc; acc += v[k]; }
            } else {
                #pragma unroll
                for (int k = 0; k < 25; ++k){ off[(b*CHK + c0 + k)*DIM + d] = acc; acc += v[k]; }
            }
        }
    } else if (tid == 128){
        float sacc = 0.f, sv[25];
        #pragma unroll
        for (int t = 0; t < 5; ++t){
            const int c0 = doP ? (4-t)*25 : t*25;
            #pragma unroll
            for (int k = 0; k < 25; ++k) sv[k] = schunk[b*CHK + c0 + k];
            if (doP){
                #pragma unroll
                for (int k = 24; k >= 0; --k){ soff[b*CHK + c0 + k] = sacc; sacc += sv[k]; }
            } else {
                #pragma unroll
                for (int k = 0; k < 25; ++k){ soff[b*CHK + c0 + k] = sacc; sacc += sv[k]; }
            }
        }
    }
}

// ------------- output fused: numer = sps*(localP[lo]+offP[c]) + sns*(localN[lo]+offN[c])
__global__ __launch_bounds__(128) void out16f_k(const float* __restrict__ e1p,
    const float* __restrict__ e2s, const float* __restrict__ e2m,
    const float* __restrict__ localP, const float* __restrict__ localN,
    const float* __restrict__ lposs, const float* __restrict__ lnegs,
    const float* __restrict__ offP, const float* __restrict__ offN,
    const float* __restrict__ soffP, const float* __restrict__ soffN,
    float* __restrict__ h)
{
    __shared__ int   slo[CKS];
    __shared__ float sps[CKS], sns[CKS];
    const int b = blockIdx.x / CHK, c = blockIdx.x % CHK, d = threadIdx.x;
    const int base = b*NNODE, r0 = c*CKS;
    const size_t pb = (size_t)b*NP1;

    if (d < CKS){
        int row = base + r0 + d;
        float e1v = e1p[row];
        float s = e1v + e2m[b];
        float m = (s >= 0.f) ? s : 0.2f*s;
        sps[d] = __expf(s - m);
        sns[d] = __expf(0.2f*s - m);
        const float* es = e2s + base;
        float tt = -e1v;
        int lo = 0, hi = NNODE;
        while (lo < hi){ int mid = (lo+hi) >> 1; if (es[mid] < tt) lo = mid+1; else hi = mid; }
        slo[d] = lo;
    }
    __syncthreads();
    #pragma unroll 4
    for (int k = 0; k < CKS; ++k){
        int row = base + r0 + k;
        int lo = slo[k];
        int cl = lo >> 4; if (cl > CHK-1) cl = CHK-1;   // lo==NNODE -> chunk 124
        size_t kb = pb + lo;
        int ob = b*CHK + cl;
        float pP = localP[kb*DIM + d] + offP[(size_t)ob*DIM + d];
        float pN = localN[kb*DIM + d] + offN[(size_t)ob*DIM + d];
        float numer = sps[k]*pP + sns[k]*pN;
        float Z     = sps[k]*(lposs[kb] + soffP[ob]) + sns[k]*(lnegs[kb] + soffN[ob]);
        float q = numer / Z;
        h[(size_t)row*DIM + d] = (q > 0.f) ? q : ((q == q) ? 0.f : q);
    }
}

extern "C" void kernel_launch(void* const* d_in, const int* in_sizes, int n_in,
                              void* d_out, int out_size, void* d_ws, size_t ws_size,
                              hipStream_t stream)
{
    (void)in_sizes; (void)n_in; (void)out_size; (void)ws_size;

    float* f = (float*)d_ws;
    float* flag    = f;  f += 4;
    float* cvt     = f;  f += CVT_TOT;                 // 0.56 MB
    float* h       = f;  f += (size_t)BN*DIM;          // 16.4 MB
    float* Wh      = f;  f += (size_t)BN*DIM;          // 16.4 MB
    float* Ppos    = f;  f += (size_t)BATCH*NP1*DIM;   // 16.4 MB  (localP)
    float* Pneg    = f;  f += (size_t)BATCH*NP1*DIM;   // 16.4 MB  (localN)
    float* chunkP  = f;  f += BATCH*CHK*DIM;           // 1 MB
    float* chunkN  = f;  f += BATCH*CHK*DIM;           // 1 MB
    float* offP    = f;  f += BATCH*CHK*DIM;           // 1 MB
    float* offN    = f;  f += BATCH*CHK*DIM;           // 1 MB
    float* schunkP = f;  f += BATCH*CHK;
    float* schunkN = f;  f += BATCH*CHK;
    float* soffP   = f;  f += BATCH*CHK;
    float* soffN   = f;  f += BATCH*CHK;
    float* e1p     = f;  f += BN;                      // full e1
    float* e2p     = f;  f += BN;                      // full e2
    float* e2s     = f;  f += BN;
    float* wp      = f;  f += BN;
    float* wn      = f;  f += BN;
    float* pposs   = f;  f += BATCH*NP1;               // lposs
    float* pnegs   = f;  f += BATCH*NP1;               // lnegs
    float* e2m     = f;  f += 16;
    int*   sidx    = (int*)f;
    unsigned short* pk = (unsigned short*)(sidx + BN);   // 16B-aligned (all counts %4==0)
    float* wa      = (float*)(pk + PK_TOT);              // 3 layers x {wa1,wa2}[128]
    float* u12     = wa + 768;                           // u1[128], u2[128]
    float* bfuse   = u12 + 256;                          // b1@W0 [128]
    float* su      = bfuse + 128;                        // s1, s2

    // 1. convert all inputs to fp32 (sniff embedded)
    InPtrs ip;
    for (int i = 0; i < 10; ++i) ip.p[i] = d_in[i];
    convert_all_k<<<(CVT_TOT+255)/256, 256, 0, stream>>>(ip, cvt, flag);

    // 2. pack W layers 1,2 + proj; wa = W@a.  3. fused-encoder weights for layer 0.
    prep_k<<<4, 256, 0, stream>>>(cvt, pk, wa);
    prep2_k<<<130, 128, 0, stream>>>(cvt, pk, wa, u12, bfuse, su);

    // 4. GAT layers (exact separable-softmax factorization); layer 0 folds encoder
    for (int l = 0; l < NLAYER; ++l){
        if (l == 0)
            gat0mfma_k<<<BN/64, 256, 0, stream>>>(cvt, pk + PK_GAT(0), u12, su, bfuse,
                                                  Wh, e1p, e2p);
        else
            gatmfma_k<<<BN/64, 256, 0, stream>>>(h, pk + PK_GAT(l), wa + l*256, Wh, e1p, e2p);
        sort_k<<<BATCH, 1024, 0, stream>>>(e2p, e2s, sidx, wp, wn, e2m);
        passAC_k<<<BATCH*CHK, DIM, 0, stream>>>(Wh, sidx, wp, wn, Ppos, Pneg, pposs, pnegs,
                                                chunkP, chunkN, schunkP, schunkN);
        passB_k<<<dim3(BATCH, 2), 256, 0, stream>>>(chunkP, chunkN, schunkP, schunkN,
                                                    offP, offN, soffP, soffN);
        out16f_k<<<BATCH*CHK, DIM, 0, stream>>>(e1p, e2s, e2m, Ppos, Pneg, pposs, pnegs,
                                                offP, offN, soffP, soffN, h);
    }

    // 5. projection (split-bf16 MFMA), output dtype per flag
    projmfma_k<<<BN/64, 256, 0, stream>>>(h, pk + PK_PROJ, cvt + OFF_PB, d_out, flag);
}